// Round 2
// baseline (1948.869 us; speedup 1.0000x reference)
//
#include <hip/hip_runtime.h>
#include <hip/hip_bf16.h>

#define BATCH 8
#define HH 128
#define WW 128
#define CC 256
#define OCC 512

typedef __bf16 bf16x8 __attribute__((ext_vector_type(8)));
typedef float f32x4 __attribute__((ext_vector_type(4)));

// Weights: K[tap][ic][oc] (f32, HWIO) -> Wt[tap][n][ic] (bf16), with the oc
// axis PERMUTED: n -> oc(n) = 2*(n&255) + (n>>8), so that in the GEMM the
// N index n gives p = n&255 (consecutive across lanes) and parity = n>>8
// (uniform per 128-wide block chunk).
__global__ void prep_weights(const float* __restrict__ k, __bf16* __restrict__ wt) {
    const int n   = blockIdx.x & 511;
    const int tap = blockIdx.x >> 9;
    const int ic  = threadIdx.x;
    const int oc  = ((n & 255) << 1) | (n >> 8);
    wt[((size_t)(tap * OCC + n)) * CC + ic] = (__bf16)k[((size_t)(tap * CC + ic)) * OCC + oc];
}

// Transpose x (b,i,j,p) NHWC -> xt (b,p,i,j) channel-planar.
__global__ __launch_bounds__(256)
void transpose_x(const float* __restrict__ x, float* __restrict__ xt) {
    __shared__ float tile[64][65];
    const int pt = blockIdx.x & 3;          // p tile (64 wide)
    const int mt = (blockIdx.x >> 2) & 255; // pixel tile (64 wide)
    const int b  = blockIdx.x >> 10;
    const int m0 = mt * 64;
    const int p0 = pt * 64;
    const int tl = threadIdx.x & 63;
    const int tr = threadIdx.x >> 6;

    const float* xb = x + (size_t)b * (HH * WW * CC);
#pragma unroll
    for (int rr = 0; rr < 16; ++rr) {
        const int m = rr * 4 + tr;
        tile[m][tl] = xb[(size_t)(m0 + m) * CC + p0 + tl];
    }
    __syncthreads();
    float* xtb = xt + (size_t)b * (CC * HH * WW);
#pragma unroll
    for (int rr = 0; rr < 16; ++rr) {
        const int p = rr * 4 + tr;
        xtb[(size_t)(p0 + p) * (HH * WW) + m0 + tl] = tile[tl][p];
    }
}

// Fused: conv row `cr` x n-tile (128 wide) as a 128x128x2304 bf16 MFMA GEMM,
// then in-lane unscramble + bilinear sample from channel-planar xt.
template <bool PLANAR>
__global__ __launch_bounds__(256)
void conv_offset_sample(const float* __restrict__ x, const float* __restrict__ xt,
                        const __bf16* __restrict__ wt,
                        const float* __restrict__ bias, float* __restrict__ out) {
    const int bi  = blockIdx.x;
    const int ncb = bi & 3;          // n chunk 0..3
    const int cr  = (bi >> 2) & 127; // conv row 0..127
    const int b   = bi >> 9;         // batch 0..7
    const int n0  = ncb * 128;

    const int tid  = threadIdx.x;
    const int lane = tid & 63;
    const int wid  = tid >> 6;   // 4 waves
    const int wm   = wid >> 1;   // 0..1 (M half)
    const int wn   = wid & 1;    // 0..1 (N half)
    const int l15  = lane & 15;
    const int lg   = lane >> 4;

    const float* xb = x + (size_t)b * (HH * WW * CC);

    f32x4 acc[4][4] = {};

#pragma unroll 1
    for (int tap = 0; tap < 9; ++tap) {
        const int dy = tap / 3 - 1;
        const int dx = tap - (tap / 3) * 3 - 1;
        const int row = cr + dy;
        const bool rowok = (unsigned)row < (unsigned)HH;
        const float* xrow = xb + row * (WW * CC);
        const __bf16* wtap = wt + (size_t)tap * (OCC * CC);

        for (int icc = 0; icc < CC; icc += 32) {
            const int ic = icc + lg * 8;

            bf16x8 afrag[4];
#pragma unroll
            for (int mi = 0; mi < 4; ++mi) {
                const int col = wm * 64 + mi * 16 + l15 + dx;
                f32x4 v0 = {0.f, 0.f, 0.f, 0.f};
                f32x4 v1 = {0.f, 0.f, 0.f, 0.f};
                if (rowok && (unsigned)col < (unsigned)WW) {
                    const f32x4* p = (const f32x4*)(xrow + col * CC + ic);
                    v0 = p[0];
                    v1 = p[1];
                }
                bf16x8 a;
                a[0] = (__bf16)v0[0]; a[1] = (__bf16)v0[1];
                a[2] = (__bf16)v0[2]; a[3] = (__bf16)v0[3];
                a[4] = (__bf16)v1[0]; a[5] = (__bf16)v1[1];
                a[6] = (__bf16)v1[2]; a[7] = (__bf16)v1[3];
                afrag[mi] = a;
            }

            bf16x8 bfrag[4];
#pragma unroll
            for (int ni = 0; ni < 4; ++ni) {
                const int n = n0 + wn * 64 + ni * 16 + l15;
                bfrag[ni] = *(const bf16x8*)(wtap + (size_t)n * CC + ic);
            }

#pragma unroll
            for (int mi = 0; mi < 4; ++mi)
#pragma unroll
                for (int ni = 0; ni < 4; ++ni)
                    acc[mi][ni] = __builtin_amdgcn_mfma_f32_16x16x32_bf16(
                        afrag[mi], bfrag[ni], acc[mi][ni], 0, 0, 0);
        }
    }

    // ---- Epilogue: unscramble + bilinear sampling (all in-lane) ----
    // conv(b, cr, j, oc) is component k=j&1 of output
    //   (b, i2 = (cr>>1) + 64*(oc&1), j2 = (cr&1)*64 + (j>>1), p = oc>>1)
    // with permuted weights: n -> oc = 2*(n&255) + (n>>8), so p = n&255,
    // par = n>>8 (uniform per block).
    const int ibase = cr >> 1;
    const int jbase = (cr & 1) * 64;

#pragma unroll
    for (int ni = 0; ni < 4; ++ni) {
        const int n   = n0 + wn * 64 + ni * 16 + l15;
        const int p   = n & 255;
        const int par = n >> 8;
        const int i2  = ibase + (par << 6);
        const float bv = bias[2 * p + par];

        const float* plane;
        if (PLANAR) {
            plane = xt + (size_t)(b * CC + p) * (HH * WW);
        } else {
            plane = x + (size_t)b * (HH * WW * CC) + p;
        }
        float* op = out + (((size_t)b * HH + i2) * WW) * CC + p;

#pragma unroll
        for (int mi = 0; mi < 4; ++mi) {
#pragma unroll
            for (int s = 0; s < 2; ++s) {
                // acc row = lg*4 + (2s+k); conv j = wm*64 + mi*16 + lg*4 + 2s + k
                const int u  = wm * 32 + mi * 8 + lg * 2 + s; // = j>>1
                const int j2 = jbase + u;

                float c0 = acc[mi][ni][2 * s]     + bv + (float)i2; // row coord
                float c1 = acc[mi][ni][2 * s + 1] + bv + (float)j2; // col coord
                c0 = fminf(fmaxf(c0, 0.f), 127.f);
                c1 = fminf(fmaxf(c1, 0.f), 127.f);

                const int lt0 = (int)floorf(c0);
                const int rb0 = (int)ceilf(c0);
                const int lt1 = (int)floorf(c1);
                const int rb1 = (int)ceilf(c1);
                const float f0 = c0 - (float)lt0;
                const float f1 = c1 - (float)lt1;

                float vlt, vrb, vlb, vrt;
                if (PLANAR) {
                    vlt = plane[(lt0 << 7) + lt1];
                    vrb = plane[(rb0 << 7) + rb1];
                    vlb = plane[(lt0 << 7) + rb1];
                    vrt = plane[(rb0 << 7) + lt1];
                } else {
                    vlt = plane[((lt0 << 7) + lt1) << 8];
                    vrb = plane[((rb0 << 7) + rb1) << 8];
                    vlb = plane[((lt0 << 7) + rb1) << 8];
                    vrt = plane[((rb0 << 7) + lt1) << 8];
                }

                const float vt = vlt + (vrt - vlt) * f0;
                const float vb = vlb + (vrb - vlb) * f0;
                op[(size_t)j2 * CC] = vt + (vb - vt) * f1;
            }
        }
    }
}

extern "C" void kernel_launch(void* const* d_in, const int* in_sizes, int n_in,
                              void* d_out, int out_size, void* d_ws, size_t ws_size,
                              hipStream_t stream) {
    const float* x    = (const float*)d_in[0];
    const float* kern = (const float*)d_in[1];
    const float* bias = (const float*)d_in[2];
    float* out = (float*)d_out;

    __bf16* wt = (__bf16*)d_ws;  // 9*512*256*2 = 2,359,296 bytes
    const size_t XT_OFF = 4u * 1024u * 1024u;
    const size_t XT_BYTES = (size_t)BATCH * CC * HH * WW * 4;  // 134,217,728
    float* xt = (float*)((char*)d_ws + XT_OFF);
    const bool planar = (ws_size >= XT_OFF + XT_BYTES);

    prep_weights<<<4608, 256, 0, stream>>>(kern, wt);
    if (planar) {
        transpose_x<<<8192, 256, 0, stream>>>(x, xt);
        conv_offset_sample<true><<<4096, 256, 0, stream>>>(x, xt, wt, bias, out);
    } else {
        conv_offset_sample<false><<<4096, 256, 0, stream>>>(x, xt, wt, bias, out);
    }
}

// Round 4
// 1488.225 us; speedup vs baseline: 1.3095x; 1.3095x over previous
//
#include <hip/hip_runtime.h>
#include <hip/hip_bf16.h>

#define BATCH 8
#define HH 128
#define WW 128
#define CC 256
#define OCC 512

typedef __bf16 bf16x8 __attribute__((ext_vector_type(8)));
typedef unsigned int u32x4 __attribute__((ext_vector_type(4)));
typedef float f32x4 __attribute__((ext_vector_type(4)));

// ws layout (bytes):
//   wt   @ 0          size 2,359,296   (9*512*256 bf16, oc-permuted)
//   zrow @ 2,359,296  size 65,536      (one zero x-row, bf16)
//   xtb  @ 2,424,832  size 67,108,864  (planar bf16 x[b][p][i][j])
//   xbf  @ 69,533,696 size 67,108,864  (NHWC bf16 x[b][i][j][ic])
#define WT_OFF   0
#define ZROW_OFF 2359296
#define XTB_OFF  2424832
#define XBF_OFF  69533696

// Weights: K[tap][ic][oc] (f32 HWIO) -> Wt[tap][n][ic] (bf16), oc permuted:
// n -> oc(n) = 2*(n&255) + (n>>8)  =>  p = n&255, parity = n>>8.
__global__ void prep_weights(const float* __restrict__ k, __bf16* __restrict__ wt) {
    const int n   = blockIdx.x & 511;
    const int tap = blockIdx.x >> 9;
    const int ic  = threadIdx.x;
    const int oc  = ((n & 255) << 1) | (n >> 8);
    wt[((size_t)(tap * OCC + n)) * CC + ic] = (__bf16)k[((size_t)(tap * CC + ic)) * OCC + oc];
}

__global__ void zero_fill(float* __restrict__ z) {
    z[blockIdx.x * 256 + threadIdx.x] = 0.0f;
}

// x (f32 NHWC) -> xbf (bf16 NHWC) and xtb (bf16 planar [b][p][m])
__global__ __launch_bounds__(256)
void prep_x(const float* __restrict__ x, __bf16* __restrict__ xbf, __bf16* __restrict__ xtb) {
    __shared__ float tile[64][65];
    const int pt = blockIdx.x & 3;
    const int mt = (blockIdx.x >> 2) & 255;
    const int b  = blockIdx.x >> 10;
    const int m0 = mt * 64, p0 = pt * 64;
    const int tl = threadIdx.x & 63, tr = threadIdx.x >> 6;

    const float* xb = x + (size_t)b * (HH * WW * CC);
    __bf16* xbfb = xbf + (size_t)b * (HH * WW * CC);
#pragma unroll
    for (int rr = 0; rr < 16; ++rr) {
        const int m = rr * 4 + tr;
        const float v = xb[(size_t)(m0 + m) * CC + p0 + tl];
        tile[m][tl] = v;
        xbfb[(size_t)(m0 + m) * CC + p0 + tl] = (__bf16)v;
    }
    __syncthreads();
    __bf16* xtbb = xtb + (size_t)b * (CC * HH * WW);
#pragma unroll
    for (int rr = 0; rr < 16; ++rr) {
        const int p = rr * 4 + tr;
        xtbb[(size_t)(p0 + p) * (HH * WW) + m0 + tl] = (__bf16)tile[tl][p];
    }
}

__device__ __forceinline__ void gload16(const void* g, void* l) {
    __builtin_amdgcn_global_load_lds(
        (const __attribute__((address_space(1))) void*)g,
        (__attribute__((address_space(3))) void*)l, 16, 0, 0);
}

// Stage one (row, ic-half) chunk: LDS logical [128 col][128 ic] bf16 = 32 KB,
// stored XOR-swizzled (byte ^= (col&7)<<4) via pre-swizzled SOURCE address.
__device__ __forceinline__ void stage_chunk(const __bf16* __restrict__ srcrow, int h,
                                            __bf16* ldsbuf, int wid, int lane) {
    const int sub = lane >> 4;          // which col in the 4-col group
    const int icb = (lane & 15) * 16;   // linear byte within the col's 256B chunk
#pragma unroll
    for (int t = 0; t < 8; ++t) {
        const int col = (wid * 8 + t) * 4 + sub;
        const int srcoff = col * 512 + h * 256 + (icb ^ ((col & 7) << 4));
        gload16((const char*)srcrow + srcoff, (char*)ldsbuf + (wid * 8 + t) * 1024);
    }
}

// Block = (b, cr, nc): conv row cr x n-chunk(128) as 128x128x2304 bf16 GEMM,
// A from LDS (global_load_lds staged, swizzled), B from global (L2-resident),
// then in-lane unscramble + bilinear sample from planar bf16 xtb.
__global__ __launch_bounds__(256, 2)
void conv_offset_sample(const __bf16* __restrict__ xbf, const __bf16* __restrict__ xtb,
                        const __bf16* __restrict__ zrow, const __bf16* __restrict__ wt,
                        const float* __restrict__ bias, float* __restrict__ out) {
    __shared__ __bf16 lds_a[2][16384];  // 2 x 32 KB

    // XCD-bijective swizzle (nwg=4096): XCD k owns bi in [k*512,(k+1)*512) = batch k
    const int orig = blockIdx.x;
    const int bi = (orig & 7) * 512 + (orig >> 3);
    const int nc = bi & 3;
    const int cr = (bi >> 2) & 127;
    const int b  = bi >> 9;

    const int tid  = threadIdx.x;
    const int lane = tid & 63;
    const int wid  = tid >> 6;  // 4 waves; wave owns rows [wid*32, wid*32+32)
    const int l15  = lane & 15;
    const int lg   = lane >> 4;

    f32x4 acc[2][8] = {};

    // prologue: stage chunk 0 (r=0 -> x row cr-1, ic half 0)
    {
        const int rg = cr - 1;
        const __bf16* srcrow = ((unsigned)rg < 128u) ? xbf + ((size_t)(b * 128 + rg) << 15) : zrow;
        stage_chunk(srcrow, 0, lds_a[0], wid, lane);
    }
    __syncthreads();

    int cur = 0;
#pragma unroll 1
    for (int idx = 0; idx < 6; ++idx) {
        if (idx < 5) {  // stage next chunk into the other buffer (overlaps compute)
            const int n2 = idx + 1;
            const int rg = cr + (n2 >> 1) - 1;
            const __bf16* srcrow = ((unsigned)rg < 128u) ? xbf + ((size_t)(b * 128 + rg) << 15) : zrow;
            stage_chunk(srcrow, n2 & 1, lds_a[cur ^ 1], wid, lane);
        }
        const int r = idx >> 1;   // dy chunk 0..2
        const int h = idx & 1;    // ic half
        const __bf16* Ab = lds_a[cur];
        const int colb = wid * 32;

#pragma unroll
        for (int dx = 0; dx < 3; ++dx) {
            const __bf16* wtap = wt + ((size_t)((r * 3 + dx) * OCC + nc * 128)) * CC + h * 128;
#pragma unroll
            for (int kk = 0; kk < 4; ++kk) {
                bf16x8 a[2];
#pragma unroll
                for (int mi = 0; mi < 2; ++mi) {
                    const int ca = colb + mi * 16 + l15 + dx - 1;
                    const unsigned msk = ((unsigned)ca < 128u) ? 0xFFFFFFFFu : 0u;
                    const int ad = (((ca & 127) << 8) + ((kk * 32 + lg * 8) << 1)) ^ ((ca & 7) << 4);
                    u32x4 uv = *(const u32x4*)((const char*)Ab + ad);
                    uv &= msk;
                    a[mi] = __builtin_bit_cast(bf16x8, uv);
                }
#pragma unroll
                for (int ni = 0; ni < 8; ++ni) {
                    const bf16x8 bv = *(const bf16x8*)(wtap + (ni * 16 + l15) * CC + kk * 32 + lg * 8);
                    acc[0][ni] = __builtin_amdgcn_mfma_f32_16x16x32_bf16(a[0], bv, acc[0][ni], 0, 0, 0);
                    acc[1][ni] = __builtin_amdgcn_mfma_f32_16x16x32_bf16(a[1], bv, acc[1][ni], 0, 0, 0);
                }
            }
        }
        __syncthreads();
        cur ^= 1;
    }

    // ---- Epilogue: unscramble + bilinear sample (in-lane) ----
    // conv(b,cr,j,oc): k=j&1 component of output (b, i2=(cr>>1)+64*(oc&1),
    // j2=(cr&1)*64+(j>>1), p=oc>>1); permuted n: p=n&255, par=n>>8.
    const int jbase = (cr & 1) << 6;
    const int par = nc >> 1;
    const int i2  = (cr >> 1) + (par << 6);
    const float fi2 = (float)i2;

#pragma unroll
    for (int ni = 0; ni < 8; ++ni) {
        const int p = ((nc & 1) << 7) + ni * 16 + l15;
        const float bv = bias[2 * p + par];
        const __bf16* plane = xtb + ((size_t)(b * 256 + p) << 14);
        float* op = out + (((size_t)(b * 128 + i2)) << 7) * 256 + p;

#pragma unroll
        for (int mi = 0; mi < 2; ++mi) {
#pragma unroll
            for (int s = 0; s < 2; ++s) {
                // conv j = wid*32 + mi*16 + lg*4 + 2s + k  ->  u = j>>1
                const int u  = wid * 16 + mi * 8 + lg * 2 + s;
                const int j2 = jbase + u;

                float c0 = acc[mi][ni][2 * s]     + bv + fi2;        // row coord
                float c1 = acc[mi][ni][2 * s + 1] + bv + (float)j2;  // col coord
                c0 = fminf(fmaxf(c0, 0.f), 127.f);
                c1 = fminf(fmaxf(c1, 0.f), 127.f);

                const int lt0 = (int)floorf(c0);
                const int rb0 = (int)ceilf(c0);
                const int lt1 = (int)floorf(c1);
                const int rb1 = (int)ceilf(c1);
                const float f0 = c0 - (float)lt0;
                const float f1 = c1 - (float)lt1;

                const float vlt = (float)plane[(lt0 << 7) + lt1];
                const float vrb = (float)plane[(rb0 << 7) + rb1];
                const float vlb = (float)plane[(lt0 << 7) + rb1];
                const float vrt = (float)plane[(rb0 << 7) + lt1];

                const float vt = vlt + (vrt - vlt) * f0;
                const float vb = vlb + (vrb - vlb) * f0;
                op[(size_t)j2 * 256] = vt + (vb - vt) * f1;
            }
        }
    }
}

extern "C" void kernel_launch(void* const* d_in, const int* in_sizes, int n_in,
                              void* d_out, int out_size, void* d_ws, size_t ws_size,
                              hipStream_t stream) {
    const float* x    = (const float*)d_in[0];
    const float* kern = (const float*)d_in[1];
    const float* bias = (const float*)d_in[2];
    float* out = (float*)d_out;

    __bf16* wt   = (__bf16*)((char*)d_ws + WT_OFF);
    __bf16* zrow = (__bf16*)((char*)d_ws + ZROW_OFF);
    __bf16* xtb  = (__bf16*)((char*)d_ws + XTB_OFF);
    __bf16* xbf  = (__bf16*)((char*)d_ws + XBF_OFF);

    prep_weights<<<4608, 256, 0, stream>>>(kern, wt);
    zero_fill<<<64, 256, 0, stream>>>((float*)zrow);
    prep_x<<<8192, 256, 0, stream>>>(x, xbf, xtb);
    conv_offset_sample<<<4096, 256, 0, stream>>>(xbf, xtb, zrow, wt, bias, out);
}